// Round 1
// baseline (367.090 us; speedup 1.0000x reference)
//
#include <hip/hip_runtime.h>

#define DIM 1024
#define D4 (DIM / 4)

// ---------------------------------------------------------------------------
// Pass 1: per-tier abs-max of (tw * ts). ts broadcasts along rows (shape [1,DIM]).
// Result written as uint bit-pattern via atomicMax (valid: abs() is >= 0, and
// IEEE non-negative floats compare identically as unsigned ints).
// Max is order-independent -> bit-exact vs numpy regardless of reduction order.
// ---------------------------------------------------------------------------
__global__ void tier_absmax_kernel(const float* __restrict__ tw,
                                   const float* __restrict__ ts,
                                   long n4, unsigned* __restrict__ out) {
    __shared__ float smax[16];
    const float4* tw4 = (const float4*)tw;
    const float4* ts4 = (const float4*)ts;
    long idx    = (long)blockIdx.x * blockDim.x + threadIdx.x;
    long stride = (long)gridDim.x * blockDim.x;
    float m = 0.0f;
    for (long i = idx; i < n4; i += stride) {
        float4 v = tw4[i];
        float4 s = ts4[i & (D4 - 1)];   // DIM=1024 -> 256 float4 per row
        m = fmaxf(m, fabsf(v.x * s.x));
        m = fmaxf(m, fabsf(v.y * s.y));
        m = fmaxf(m, fabsf(v.z * s.z));
        m = fmaxf(m, fabsf(v.w * s.w));
    }
    // wave(64)-level reduce
    for (int off = 32; off > 0; off >>= 1)
        m = fmaxf(m, __shfl_down(m, off));
    int lane = threadIdx.x & 63;
    int wave = threadIdx.x >> 6;
    if (lane == 0) smax[wave] = m;
    __syncthreads();
    if (threadIdx.x == 0) {
        int nwaves = blockDim.x >> 6;
        float bm = smax[0];
        for (int w = 1; w < nwaves; ++w) bm = fmaxf(bm, smax[w]);
        atomicMax(out, __float_as_uint(bm));
    }
}

// ---------------------------------------------------------------------------
// Pass 2: gather + on-the-fly fake-quant. One block (256 thr) per token;
// each thread handles one float4 of the 1024-dim row. Tier branch is
// block-uniform (all threads share the token id) -> no divergence.
// Division is IEEE (no fast-math reciprocal) to match np bit-exactly;
// rintf = round-half-to-even = np.round.
// ---------------------------------------------------------------------------
__global__ void gather_quant_kernel(const int* __restrict__ ids,
                                    const float* __restrict__ tw0,
                                    const float* __restrict__ tw1,
                                    const float* __restrict__ tw2,
                                    const float* __restrict__ tw3,
                                    const float* __restrict__ ts0,
                                    const float* __restrict__ ts1,
                                    const float* __restrict__ ts2,
                                    const float* __restrict__ ts3,
                                    const unsigned* __restrict__ amax,
                                    float* __restrict__ out) {
    int token = blockIdx.x;
    int id = ids[token];

    const float* tw; const float* ts;
    float maxval = 0.f; unsigned am = 0; bool quant = true;
    if (id < 256)        { tw = tw0 + (long)id * DIM;           ts = ts0; quant = false; }
    else if (id < 2048)  { tw = tw1 + (long)(id - 256) * DIM;   ts = ts1; maxval = 127.f; am = amax[0]; }
    else if (id < 16384) { tw = tw2 + (long)(id - 2048) * DIM;  ts = ts2; maxval = 31.f;  am = amax[1]; }
    else                 { tw = tw3 + (long)(id - 16384) * DIM; ts = ts3; maxval = 7.f;   am = amax[2]; }

    int t = threadIdx.x;            // 0..255, one float4 each
    float4 v = ((const float4*)tw)[t];
    float4 s = ((const float4*)ts)[t];
    float4 x;
    x.x = v.x * s.x; x.y = v.y * s.y; x.z = v.z * s.z; x.w = v.w * s.w;

    if (quant) {
        float scale = fmaxf(__uint_as_float(am), 1e-8f) / maxval;
        x.x = fminf(fmaxf(rintf(x.x / scale), -maxval), maxval) * scale;
        x.y = fminf(fmaxf(rintf(x.y / scale), -maxval), maxval) * scale;
        x.z = fminf(fmaxf(rintf(x.z / scale), -maxval), maxval) * scale;
        x.w = fminf(fmaxf(rintf(x.w / scale), -maxval), maxval) * scale;
    }
    ((float4*)(out + (long)token * DIM))[t] = x;
}

static inline int grid_for(long n4) {
    long g = (n4 + 255) / 256;
    if (g > 4096) g = 4096;
    if (g < 1) g = 1;
    return (int)g;
}

extern "C" void kernel_launch(void* const* d_in, const int* in_sizes, int n_in,
                              void* d_out, int out_size, void* d_ws, size_t ws_size,
                              hipStream_t stream) {
    const int*   ids = (const int*)d_in[0];
    const float* tw0 = (const float*)d_in[1];
    const float* tw1 = (const float*)d_in[2];
    const float* tw2 = (const float*)d_in[3];
    const float* tw3 = (const float*)d_in[4];
    const float* ts0 = (const float*)d_in[5];
    const float* ts1 = (const float*)d_in[6];
    const float* ts2 = (const float*)d_in[7];
    const float* ts3 = (const float*)d_in[8];
    float* out = (float*)d_out;

    unsigned* amax = (unsigned*)d_ws;    // 3 entries: tiers 1..3
    hipMemsetAsync(d_ws, 0, 3 * sizeof(unsigned), stream);

    long n1 = (long)in_sizes[2] / 4;     // tw1 float4 count
    long n2 = (long)in_sizes[3] / 4;
    long n3 = (long)in_sizes[4] / 4;

    tier_absmax_kernel<<<grid_for(n1), 256, 0, stream>>>(tw1, ts1, n1, amax + 0);
    tier_absmax_kernel<<<grid_for(n2), 256, 0, stream>>>(tw2, ts2, n2, amax + 1);
    tier_absmax_kernel<<<grid_for(n3), 256, 0, stream>>>(tw3, ts3, n3, amax + 2);

    int n_tokens = in_sizes[0];          // 8 * 2048 = 16384
    gather_quant_kernel<<<n_tokens, 256, 0, stream>>>(
        ids, tw0, tw1, tw2, tw3, ts0, ts1, ts2, ts3, amax, out);
}

// Round 3
// 298.915 us; speedup vs baseline: 1.2281x; 1.2281x over previous
//
#include <hip/hip_runtime.h>

#define DIM 1024
#define D4  (DIM / 4)

typedef float vfloat4 __attribute__((ext_vector_type(4)));  // native vec for nontemporal builtin

// ---------------------------------------------------------------------------
// Pass 1 (single launch): per-tier abs-max of (tw * ts) for tiers 1..3.
// Blocks [0,b1) scan tier1, [b1,b2) tier2, [b2,grid) tier3 — partitioned
// proportional to tier bytes so all three streams finish together.
// Max is order-independent -> bit-exact vs numpy; atomicMax on the uint bit
// pattern is valid for non-negative floats.
// ---------------------------------------------------------------------------
__global__ __launch_bounds__(256) void absmax3_kernel(
    const float4* __restrict__ tw1, const float4* __restrict__ ts1, long n1,
    const float4* __restrict__ tw2, const float4* __restrict__ ts2, long n2,
    const float4* __restrict__ tw3, const float4* __restrict__ ts3, long n3,
    int b1, int b2, unsigned* __restrict__ amax)
{
    __shared__ float smax[4];
    int bid = blockIdx.x;
    const float4 *tw, *ts; long n4; int blo, bhi; unsigned* out;
    if (bid < b1)      { tw = tw1; ts = ts1; n4 = n1; blo = 0;  bhi = b1;        out = amax + 0; }
    else if (bid < b2) { tw = tw2; ts = ts2; n4 = n2; blo = b1; bhi = b2;        out = amax + 1; }
    else               { tw = tw3; ts = ts3; n4 = n3; blo = b2; bhi = gridDim.x; out = amax + 2; }

    long idx    = (long)(bid - blo) * blockDim.x + threadIdx.x;
    long stride = (long)(bhi - blo) * blockDim.x;
    float m = 0.0f;
    for (long i = idx; i < n4; i += stride) {
        float4 v = tw[i];
        float4 s = ts[i & (D4 - 1)];    // ts is [1,DIM], broadcast along rows
        m = fmaxf(m, fmaxf(fmaxf(fabsf(v.x * s.x), fabsf(v.y * s.y)),
                           fmaxf(fabsf(v.z * s.z), fabsf(v.w * s.w))));
    }
    // wave(64) reduce, then 4 waves -> block, then one atomic
    for (int off = 32; off > 0; off >>= 1)
        m = fmaxf(m, __shfl_down(m, off));
    if ((threadIdx.x & 63) == 0) smax[threadIdx.x >> 6] = m;
    __syncthreads();
    if (threadIdx.x == 0) {
        float bm = fmaxf(fmaxf(smax[0], smax[1]), fmaxf(smax[2], smax[3]));
        atomicMax(out, __float_as_uint(bm));
    }
}

// ---------------------------------------------------------------------------
// Pass 2: gather + on-the-fly fake-quant. One block (256 thr) per token; each
// thread handles one float4 of the 1024-dim row. Tier branch is block-uniform.
// IEEE division (no rcp) + rintf (half-even) to match numpy; nontemporal
// store keeps the freshly-scanned 205 MB table resident in L3.
// ---------------------------------------------------------------------------
__global__ __launch_bounds__(256) void gather_quant_kernel(
    const int* __restrict__ ids,
    const float* __restrict__ tw0, const float* __restrict__ tw1,
    const float* __restrict__ tw2, const float* __restrict__ tw3,
    const float* __restrict__ ts0, const float* __restrict__ ts1,
    const float* __restrict__ ts2, const float* __restrict__ ts3,
    const unsigned* __restrict__ amax, float* __restrict__ out)
{
    int token = blockIdx.x;
    int id = ids[token];

    const float* tw; const float* ts;
    float maxval = 0.f; unsigned am = 0; bool quant = true;
    if (id < 256)        { tw = tw0 + (long)id * DIM;           ts = ts0; quant = false; }
    else if (id < 2048)  { tw = tw1 + (long)(id - 256) * DIM;   ts = ts1; maxval = 127.f; am = amax[0]; }
    else if (id < 16384) { tw = tw2 + (long)(id - 2048) * DIM;  ts = ts2; maxval = 31.f;  am = amax[1]; }
    else                 { tw = tw3 + (long)(id - 16384) * DIM; ts = ts3; maxval = 7.f;   am = amax[2]; }

    int t = threadIdx.x;               // 0..255, one float4 each
    float4 v = ((const float4*)tw)[t];
    float4 s = ((const float4*)ts)[t];
    vfloat4 x;
    x.x = v.x * s.x; x.y = v.y * s.y; x.z = v.z * s.z; x.w = v.w * s.w;

    if (quant) {
        float scale = fmaxf(__uint_as_float(am), 1e-8f) / maxval;
        x.x = fminf(fmaxf(rintf(x.x / scale), -maxval), maxval) * scale;
        x.y = fminf(fmaxf(rintf(x.y / scale), -maxval), maxval) * scale;
        x.z = fminf(fmaxf(rintf(x.z / scale), -maxval), maxval) * scale;
        x.w = fminf(fmaxf(rintf(x.w / scale), -maxval), maxval) * scale;
    }
    __builtin_nontemporal_store(x, (vfloat4*)(out + (long)token * DIM) + t);
}

extern "C" void kernel_launch(void* const* d_in, const int* in_sizes, int n_in,
                              void* d_out, int out_size, void* d_ws, size_t ws_size,
                              hipStream_t stream) {
    const int*   ids = (const int*)d_in[0];
    const float* tw0 = (const float*)d_in[1];
    const float* tw1 = (const float*)d_in[2];
    const float* tw2 = (const float*)d_in[3];
    const float* tw3 = (const float*)d_in[4];
    const float* ts0 = (const float*)d_in[5];
    const float* ts1 = (const float*)d_in[6];
    const float* ts2 = (const float*)d_in[7];
    const float* ts3 = (const float*)d_in[8];
    float* out = (float*)d_out;

    unsigned* amax = (unsigned*)d_ws;    // 3 entries: tiers 1..3
    (void)hipMemsetAsync(d_ws, 0, 3 * sizeof(unsigned), stream);

    long n1 = (long)in_sizes[2] / 4;     // float4 counts
    long n2 = (long)in_sizes[3] / 4;
    long n3 = (long)in_sizes[4] / 4;
    long N  = n1 + n2 + n3;

    // 2048 blocks = 8 blocks/CU x 256 CUs -> fully resident, one wave of blocks.
    const int G = 2048;
    int b1 = (int)((n1 * G + N - 1) / N); if (b1 < 1) b1 = 1;
    int b2 = b1 + (int)((n2 * G) / N);    if (b2 <= b1) b2 = b1 + 1;
    if (b2 >= G) b2 = G - 1;

    absmax3_kernel<<<G, 256, 0, stream>>>(
        (const float4*)tw1, (const float4*)ts1, n1,
        (const float4*)tw2, (const float4*)ts2, n2,
        (const float4*)tw3, (const float4*)ts3, n3,
        b1, b2, amax);

    int n_tokens = in_sizes[0];          // 8 * 2048 = 16384
    gather_quant_kernel<<<n_tokens, 256, 0, stream>>>(
        ids, tw0, tw1, tw2, tw3, ts0, ts1, ts2, ts3, amax, out);
}

// Round 4
// 290.656 us; speedup vs baseline: 1.2630x; 1.0284x over previous
//
#include <hip/hip_runtime.h>

#define DIM 1024
#define D4  (DIM / 4)

typedef float vfloat4 __attribute__((ext_vector_type(4)));  // native vec for nontemporal builtin

static __device__ __forceinline__ float4 abs_max4(float4 m, float4 v) {
    m.x = fmaxf(m.x, fabsf(v.x)); m.y = fmaxf(m.y, fabsf(v.y));
    m.z = fmaxf(m.z, fabsf(v.z)); m.w = fmaxf(m.w, fabsf(v.w));
    return m;
}

// ---------------------------------------------------------------------------
// Pass 1 (single launch): per-tier abs-max of (tw * ts), tiers 1..3.
// Blocks partitioned proportional to tier bytes. Manual x4 unroll: 4
// independent float4 loads in flight per wave (fixes the 1-load-deep MLP
// limit seen in round 3: 2.3 TB/s effective, VALUBusy 5%).
// ts is loop-invariant per thread (stride % 256 == 0) -> hoisted; since f32
// rounding is monotone, accumulating max|v| then multiplying by |s| once is
// bit-exact vs per-element |v*s|.
// ---------------------------------------------------------------------------
__global__ __launch_bounds__(256, 8) void absmax3_kernel(
    const float4* __restrict__ tw1, const float4* __restrict__ ts1, long n1,
    const float4* __restrict__ tw2, const float4* __restrict__ ts2, long n2,
    const float4* __restrict__ tw3, const float4* __restrict__ ts3, long n3,
    int b1, int b2, unsigned* __restrict__ amax)
{
    __shared__ float smax[4];
    int bid = blockIdx.x;
    const float4 *tw, *ts; long n4; int blo, bhi; unsigned* out;
    if (bid < b1)      { tw = tw1; ts = ts1; n4 = n1; blo = 0;  bhi = b1;        out = amax + 0; }
    else if (bid < b2) { tw = tw2; ts = ts2; n4 = n2; blo = b1; bhi = b2;        out = amax + 1; }
    else               { tw = tw3; ts = ts3; n4 = n3; blo = b2; bhi = gridDim.x; out = amax + 2; }

    long idx    = (long)(bid - blo) * blockDim.x + threadIdx.x;
    long stride = (long)(bhi - blo) * blockDim.x;   // multiple of 256

    float4 ma = {0,0,0,0}, mb = {0,0,0,0}, mc = {0,0,0,0}, md = {0,0,0,0};
    long i = idx;
    for (; i + 3 * stride < n4; i += 4 * stride) {
        float4 a = tw[i];
        float4 b = tw[i + stride];
        float4 c = tw[i + 2 * stride];
        float4 d = tw[i + 3 * stride];
        ma = abs_max4(ma, a); mb = abs_max4(mb, b);
        mc = abs_max4(mc, c); md = abs_max4(md, d);
    }
    for (; i < n4; i += stride) ma = abs_max4(ma, tw[i]);

    ma = abs_max4(ma, mb); mc = abs_max4(mc, md); ma = abs_max4(ma, mc);
    float4 s = ts[idx & (D4 - 1)];     // loop-invariant column quad
    float m = fmaxf(fmaxf(ma.x * fabsf(s.x), ma.y * fabsf(s.y)),
                    fmaxf(ma.z * fabsf(s.z), ma.w * fabsf(s.w)));

    for (int off = 32; off > 0; off >>= 1)
        m = fmaxf(m, __shfl_down(m, off));
    if ((threadIdx.x & 63) == 0) smax[threadIdx.x >> 6] = m;
    __syncthreads();
    if (threadIdx.x == 0) {
        float bm = fmaxf(fmaxf(smax[0], smax[1]), fmaxf(smax[2], smax[3]));
        atomicMax(out, __float_as_uint(bm));
    }
}

// ---------------------------------------------------------------------------
// Pass 2: gather + on-the-fly fake-quant. One WAVE per token (tier branch is
// wave-uniform -> no divergence); 4 waves (tokens) per block; each lane
// issues 4 independent float4 loads covering the 4 KB row (4-deep MLP).
// IEEE division + rintf (half-even) match numpy; nontemporal stores keep the
// scanned table resident in L3 for subsequent row reads.
// ---------------------------------------------------------------------------
__global__ __launch_bounds__(256) void gather_quant_kernel(
    const int* __restrict__ ids, int n_tokens,
    const float* __restrict__ tw0, const float* __restrict__ tw1,
    const float* __restrict__ tw2, const float* __restrict__ tw3,
    const float* __restrict__ ts0, const float* __restrict__ ts1,
    const float* __restrict__ ts2, const float* __restrict__ ts3,
    const unsigned* __restrict__ amax, float* __restrict__ out)
{
    int sub  = threadIdx.x >> 6;          // wave id in block = token sub-index
    int lane = threadIdx.x & 63;
    int token = blockIdx.x * 4 + sub;
    if (token >= n_tokens) return;
    int id = ids[token];

    const float* tw; const float* ts;
    float maxval = 1.f; unsigned am = 0; bool quant = true;
    if (id < 256)        { tw = tw0 + (long)id * DIM;           ts = ts0; quant = false; }
    else if (id < 2048)  { tw = tw1 + (long)(id - 256) * DIM;   ts = ts1; maxval = 127.f; am = amax[0]; }
    else if (id < 16384) { tw = tw2 + (long)(id - 2048) * DIM;  ts = ts2; maxval = 31.f;  am = amax[1]; }
    else                 { tw = tw3 + (long)(id - 16384) * DIM; ts = ts3; maxval = 7.f;   am = amax[2]; }

    const float4* twv = (const float4*)tw;
    const float4* tsv = (const float4*)ts;

    // 4 independent row loads in flight per lane
    float4 v0 = twv[lane +   0], v1 = twv[lane +  64];
    float4 v2 = twv[lane + 128], v3 = twv[lane + 192];
    float4 s0 = tsv[lane +   0], s1 = tsv[lane +  64];
    float4 s2 = tsv[lane + 128], s3 = tsv[lane + 192];

    float scale = fmaxf(__uint_as_float(am), 1e-8f) / maxval;

    float4 vv[4] = {v0, v1, v2, v3};
    float4 ss[4] = {s0, s1, s2, s3};
    float* outp = out + (long)token * DIM;
    #pragma unroll
    for (int j = 0; j < 4; ++j) {
        vfloat4 x;
        x.x = vv[j].x * ss[j].x; x.y = vv[j].y * ss[j].y;
        x.z = vv[j].z * ss[j].z; x.w = vv[j].w * ss[j].w;
        if (quant) {
            x.x = fminf(fmaxf(rintf(x.x / scale), -maxval), maxval) * scale;
            x.y = fminf(fmaxf(rintf(x.y / scale), -maxval), maxval) * scale;
            x.z = fminf(fmaxf(rintf(x.z / scale), -maxval), maxval) * scale;
            x.w = fminf(fmaxf(rintf(x.w / scale), -maxval), maxval) * scale;
        }
        __builtin_nontemporal_store(x, (vfloat4*)outp + lane + 64 * j);
    }
}

extern "C" void kernel_launch(void* const* d_in, const int* in_sizes, int n_in,
                              void* d_out, int out_size, void* d_ws, size_t ws_size,
                              hipStream_t stream) {
    const int*   ids = (const int*)d_in[0];
    const float* tw0 = (const float*)d_in[1];
    const float* tw1 = (const float*)d_in[2];
    const float* tw2 = (const float*)d_in[3];
    const float* tw3 = (const float*)d_in[4];
    const float* ts0 = (const float*)d_in[5];
    const float* ts1 = (const float*)d_in[6];
    const float* ts2 = (const float*)d_in[7];
    const float* ts3 = (const float*)d_in[8];
    float* out = (float*)d_out;

    unsigned* amax = (unsigned*)d_ws;    // 3 entries: tiers 1..3
    (void)hipMemsetAsync(d_ws, 0, 3 * sizeof(unsigned), stream);

    long n1 = (long)in_sizes[2] / 4;     // float4 counts
    long n2 = (long)in_sizes[3] / 4;
    long n3 = (long)in_sizes[4] / 4;
    long N  = n1 + n2 + n3;

    const int G = 2048;                  // 8 blocks/CU, fully resident
    int b1 = (int)((n1 * G + N - 1) / N); if (b1 < 1) b1 = 1;
    int b2 = b1 + (int)((n2 * G) / N);    if (b2 <= b1) b2 = b1 + 1;
    if (b2 >= G) b2 = G - 1;

    absmax3_kernel<<<G, 256, 0, stream>>>(
        (const float4*)tw1, (const float4*)ts1, n1,
        (const float4*)tw2, (const float4*)ts2, n2,
        (const float4*)tw3, (const float4*)ts3, n3,
        b1, b2, amax);

    int n_tokens = in_sizes[0];          // 16384
    gather_quant_kernel<<<(n_tokens + 3) / 4, 256, 0, stream>>>(
        ids, n_tokens, tw0, tw1, tw2, tw3, ts0, ts1, ts2, ts3, amax, out);
}